// Round 2
// baseline (967.756 us; speedup 1.0000x reference)
//
#include <hip/hip_runtime.h>
#include <math.h>

// Problem constants
#define DIMC 512
#define NHEADS 8
#define HD 64
#define HW 4096
#define NB 8
#define SCALE 0.125f
#define EPSN 1e-12f

// ---------------------------------------------------------------------------
// K1: fused QKV projection GEMM (per batch):
//   q_raw[b][j][n] = mask[b][n] * sum_c Wq[j][c] * x[b][c][n]
//   k_raw          = same with Wk
//   v              = sum_c Wv[j][c] * x[b][c][n]   (no mask)
// Tiling: 64(M=j) x 64(N=hw) block tile, BK=16, 256 threads, 4x4 micro-tile,
// three accumulator sets sharing one X tile.
// ---------------------------------------------------------------------------
__global__ __launch_bounds__(256) void qkv_gemm(
    const float* __restrict__ x, const float* __restrict__ mask,
    const float* __restrict__ Wq, const float* __restrict__ Wk,
    const float* __restrict__ Wv,
    float* __restrict__ q, float* __restrict__ k, float* __restrict__ v)
{
    const int b  = blockIdx.z;
    const int j0 = blockIdx.y * 64;
    const int n0 = blockIdx.x * 64;
    const float* X = x + (size_t)b * DIMC * HW;

    __shared__ float sX [16][64];   // [c][n]
    __shared__ float sWq[16][64];   // [c][j] (transposed)
    __shared__ float sWk[16][64];
    __shared__ float sWv[16][64];

    const int t  = threadIdx.x;
    const int tx = t & 15;          // output col group
    const int ty = t >> 4;          // output row group

    // load index helpers
    const int lxr = t >> 4;         // X tile row (c)   0..15
    const int lxc = (t & 15) * 4;   // X tile col (n)
    const int lwr = t >> 2;         // W tile row (j)   0..63
    const int lwc = (t & 3) * 4;    // W tile col (c)   0,4,8,12  (BK=16: full coverage)

    float aq[4][4] = {}, ak[4][4] = {}, av[4][4] = {};

    for (int c0 = 0; c0 < DIMC; c0 += 16) {
        float4 xv = *(const float4*)(X + (size_t)(c0 + lxr) * HW + n0 + lxc);
        *(float4*)&sX[lxr][lxc] = xv;

        float4 wq4 = *(const float4*)(Wq + (size_t)(j0 + lwr) * DIMC + c0 + lwc);
        float4 wk4 = *(const float4*)(Wk + (size_t)(j0 + lwr) * DIMC + c0 + lwc);
        float4 wv4 = *(const float4*)(Wv + (size_t)(j0 + lwr) * DIMC + c0 + lwc);
        sWq[lwc+0][lwr] = wq4.x; sWq[lwc+1][lwr] = wq4.y;
        sWq[lwc+2][lwr] = wq4.z; sWq[lwc+3][lwr] = wq4.w;
        sWk[lwc+0][lwr] = wk4.x; sWk[lwc+1][lwr] = wk4.y;
        sWk[lwc+2][lwr] = wk4.z; sWk[lwc+3][lwr] = wk4.w;
        sWv[lwc+0][lwr] = wv4.x; sWv[lwc+1][lwr] = wv4.y;
        sWv[lwc+2][lwr] = wv4.z; sWv[lwc+3][lwr] = wv4.w;
        __syncthreads();

        #pragma unroll
        for (int kk = 0; kk < 16; ++kk) {
            float4 xf  = *(float4*)&sX [kk][tx*4];
            float4 wqf = *(float4*)&sWq[kk][ty*4];
            float4 wkf = *(float4*)&sWk[kk][ty*4];
            float4 wvf = *(float4*)&sWv[kk][ty*4];
            float xr[4]  = {xf.x, xf.y, xf.z, xf.w};
            float wqr[4] = {wqf.x, wqf.y, wqf.z, wqf.w};
            float wkr[4] = {wkf.x, wkf.y, wkf.z, wkf.w};
            float wvr[4] = {wvf.x, wvf.y, wvf.z, wvf.w};
            #pragma unroll
            for (int r = 0; r < 4; ++r)
                #pragma unroll
                for (int c = 0; c < 4; ++c) {
                    aq[r][c] = fmaf(wqr[r], xr[c], aq[r][c]);
                    ak[r][c] = fmaf(wkr[r], xr[c], ak[r][c]);
                    av[r][c] = fmaf(wvr[r], xr[c], av[r][c]);
                }
        }
        __syncthreads();
    }

    // epilogue: mask applies to q,k only (mask depends only on hw column)
    float4 mv = *(const float4*)(mask + (size_t)b * HW + n0 + tx*4);
    float mm[4] = {mv.x, mv.y, mv.z, mv.w};
    const size_t obase = ((size_t)b * DIMC + j0 + ty*4) * HW + n0 + tx*4;
    #pragma unroll
    for (int r = 0; r < 4; ++r) {
        float4 oq = make_float4(aq[r][0]*mm[0], aq[r][1]*mm[1],
                                aq[r][2]*mm[2], aq[r][3]*mm[3]);
        float4 ok = make_float4(ak[r][0]*mm[0], ak[r][1]*mm[1],
                                ak[r][2]*mm[2], ak[r][3]*mm[3]);
        float4 ov = make_float4(av[r][0], av[r][1], av[r][2], av[r][3]);
        *(float4*)(q + obase + (size_t)r * HW) = oq;
        *(float4*)(k + obase + (size_t)r * HW) = ok;
        *(float4*)(v + obase + (size_t)r * HW) = ov;
    }
}

// ---------------------------------------------------------------------------
// K2: per-row (length 4096) sum-of-squares -> rsq = 1/max(||row||, eps)
// rows 0..4095 = q rows, 4096..8191 = k rows
// ---------------------------------------------------------------------------
__global__ __launch_bounds__(256) void rowsumsq(
    const float* __restrict__ q, const float* __restrict__ k,
    float* __restrict__ rsq)
{
    const int row = blockIdx.x;    // 0..8191
    const float* p = (row < 4096) ? (q + (size_t)row * HW)
                                  : (k + (size_t)(row - 4096) * HW);
    float s = 0.f;
    for (int i = threadIdx.x * 4; i < HW; i += 256 * 4) {
        float4 vv = *(const float4*)(p + i);
        s += vv.x*vv.x + vv.y*vv.y + vv.z*vv.z + vv.w*vv.w;
    }
    #pragma unroll
    for (int o = 32; o > 0; o >>= 1) s += __shfl_down(s, o, 64);
    __shared__ float red[4];
    if ((threadIdx.x & 63) == 0) red[threadIdx.x >> 6] = s;
    __syncthreads();
    if (threadIdx.x == 0) {
        float tot = red[0] + red[1] + red[2] + red[3];
        rsq[row] = 1.0f / fmaxf(sqrtf(tot), EPSN);
    }
}

// ---------------------------------------------------------------------------
// K3: partial attention logits. For each (b,h) and n-chunk of 512:
//   Spart[bh][chunk][r][c] = sum_{n in chunk} q_raw[r][n] * k_raw[c][n]
// ---------------------------------------------------------------------------
__global__ __launch_bounds__(256) void attn_partial(
    const float* __restrict__ q, const float* __restrict__ k,
    float* __restrict__ Spart)
{
    const int bh = blockIdx.x;      // 0..63
    const int chunk = blockIdx.y;   // 0..7
    const int b = bh >> 3, h = bh & 7;
    const float* Q = q + (size_t)(b * DIMC + h * HD) * HW;
    const float* K = k + (size_t)(b * DIMC + h * HD) * HW;

    __shared__ float sQ[64][65];    // [n][row], padded
    __shared__ float sK[64][65];

    const int t  = threadIdx.x;
    const int tx = t & 15, ty = t >> 4;
    float acc[4][4] = {};

    for (int nt = 0; nt < 8; ++nt) {
        const int nb = chunk * 512 + nt * 64;
        const int r0  = t >> 4;          // 0..15
        const int nn0 = (t & 15) * 4;
        #pragma unroll
        for (int i = 0; i < 4; ++i) {
            const int rr = r0 + i * 16;
            float4 qv = *(const float4*)(Q + (size_t)rr * HW + nb + nn0);
            sQ[nn0+0][rr] = qv.x; sQ[nn0+1][rr] = qv.y;
            sQ[nn0+2][rr] = qv.z; sQ[nn0+3][rr] = qv.w;
            float4 kv = *(const float4*)(K + (size_t)rr * HW + nb + nn0);
            sK[nn0+0][rr] = kv.x; sK[nn0+1][rr] = kv.y;
            sK[nn0+2][rr] = kv.z; sK[nn0+3][rr] = kv.w;
        }
        __syncthreads();
        #pragma unroll 16
        for (int nn = 0; nn < 64; ++nn) {
            float qf[4], kf[4];
            #pragma unroll
            for (int i = 0; i < 4; ++i) { qf[i] = sQ[nn][ty*4+i]; kf[i] = sK[nn][tx*4+i]; }
            #pragma unroll
            for (int r = 0; r < 4; ++r)
                #pragma unroll
                for (int c = 0; c < 4; ++c)
                    acc[r][c] = fmaf(qf[r], kf[c], acc[r][c]);
        }
        __syncthreads();
    }

    float* Sp = Spart + ((size_t)(bh * 8 + chunk) << 12) + (ty*4) * 64 + tx*4;
    #pragma unroll
    for (int r = 0; r < 4; ++r)
        *(float4*)(Sp + r * 64) = make_float4(acc[r][0], acc[r][1], acc[r][2], acc[r][3]);
}

// ---------------------------------------------------------------------------
// K4: combine partials, apply normalization + scale, row softmax.
//   attn[bh][r][c] = softmax_c( S[r][c] * rsq_q[r] * rsq_k[c] * SCALE )
// one block per (b,h); one thread per row r.
// ---------------------------------------------------------------------------
__global__ __launch_bounds__(64) void softmax_attn(
    const float* __restrict__ Spart, const float* __restrict__ rsq,
    float* __restrict__ attn)
{
    const int bh = blockIdx.x;
    const int b = bh >> 3, h = bh & 7;
    const int r = threadIdx.x;   // 0..63
    const float rq = rsq[b * DIMC + h * HD + r];
    const float* Sp = Spart + ((size_t)(bh * 8) << 12) + r * 64;

    float row[64];
    #pragma unroll 8
    for (int c = 0; c < 64; ++c) {
        float s = 0.f;
        #pragma unroll
        for (int ch = 0; ch < 8; ++ch) s += Sp[((size_t)ch << 12) + c];
        row[c] = s * SCALE * rq * rsq[4096 + b * DIMC + h * HD + c];
    }
    float mx = -1e30f;
    #pragma unroll 8
    for (int c = 0; c < 64; ++c) mx = fmaxf(mx, row[c]);
    float sum = 0.f;
    #pragma unroll 8
    for (int c = 0; c < 64; ++c) { row[c] = __expf(row[c] - mx); sum += row[c]; }
    const float inv = 1.0f / sum;
    float* A = attn + ((size_t)bh << 12) + r * 64;
    #pragma unroll 8
    for (int c = 0; c < 64; ++c) A[c] = row[c] * inv;
}

// ---------------------------------------------------------------------------
// K5: fold Wp through attn (per batch, per head):
//   Wp2[b][j][h*64+d] = sum_c Wp[j][h*64+c] * attn[b][h][c][d]
// block: (jt, h, b), 64x64 output tile, K=64
// FIX (R1): the Wp tile here is 64x64 (K=64), so each thread must stage 16
// floats (4 x float4), not 4. Previous version only filled sW columns 0..15;
// columns 16..63 were garbage LDS -> absmax ~10.8.
// ---------------------------------------------------------------------------
__global__ __launch_bounds__(256) void build_wp2(
    const float* __restrict__ Wp, const float* __restrict__ attn,
    float* __restrict__ Wp2)
{
    const int jt = blockIdx.x;   // 0..7
    const int h  = blockIdx.y;   // 0..7
    const int b  = blockIdx.z;   // 0..7

    __shared__ float sA[64][64];   // attn[c][d]
    __shared__ float sW[64][64];   // Wp   [c][j] (transposed)

    const int t = threadIdx.x;
    {
        const float* A = attn + ((size_t)(b * 8 + h) << 12);
        for (int i = t * 4; i < 4096; i += 1024)
            *(float4*)&sA[0][i] = *(const float4*)(A + i);
    }
    {
        const int j  = t >> 2;           // 0..63
        const int c0 = (t & 3) * 16;     // 0,16,32,48  -> full 64-col coverage
        #pragma unroll
        for (int i = 0; i < 4; ++i) {
            float4 w4 = *(const float4*)(Wp + (size_t)(jt*64 + j) * DIMC + h*64 + c0 + i*4);
            sW[c0+i*4+0][j] = w4.x; sW[c0+i*4+1][j] = w4.y;
            sW[c0+i*4+2][j] = w4.z; sW[c0+i*4+3][j] = w4.w;
        }
    }
    __syncthreads();

    const int tx = t & 15, ty = t >> 4;
    float acc[4][4] = {};
    #pragma unroll 16
    for (int c = 0; c < 64; ++c) {
        float wf[4], af[4];
        #pragma unroll
        for (int i = 0; i < 4; ++i) { wf[i] = sW[c][ty*4+i]; af[i] = sA[c][tx*4+i]; }
        #pragma unroll
        for (int r = 0; r < 4; ++r)
            #pragma unroll
            for (int cc = 0; cc < 4; ++cc)
                acc[r][cc] = fmaf(wf[r], af[cc], acc[r][cc]);
    }

    float* O = Wp2 + ((size_t)b * DIMC + jt*64 + ty*4) * DIMC + h*64 + tx*4;
    #pragma unroll
    for (int r = 0; r < 4; ++r)
        *(float4*)(O + (size_t)r * DIMC) = make_float4(acc[r][0], acc[r][1], acc[r][2], acc[r][3]);
}

// ---------------------------------------------------------------------------
// K6: final GEMM  out[b][j][n] = sum_c Wp2[b][j][c] * v[b][c][n]
// writes directly into NCHW d_out
// ---------------------------------------------------------------------------
__global__ __launch_bounds__(256) void gemm_final(
    const float* __restrict__ Wp2, const float* __restrict__ v,
    float* __restrict__ out)
{
    const int b  = blockIdx.z;
    const int j0 = blockIdx.y * 64;
    const int n0 = blockIdx.x * 64;
    const float* A = Wp2 + (size_t)b * DIMC * DIMC;
    const float* X = v   + (size_t)b * DIMC * HW;

    __shared__ float sX[16][64];
    __shared__ float sW[16][64];

    const int t  = threadIdx.x;
    const int tx = t & 15, ty = t >> 4;
    const int lxr = t >> 4, lxc = (t & 15) * 4;
    const int lwr = t >> 2, lwc = (t & 3) * 4;

    float acc[4][4] = {};
    for (int c0 = 0; c0 < DIMC; c0 += 16) {
        *(float4*)&sX[lxr][lxc] = *(const float4*)(X + (size_t)(c0 + lxr) * HW + n0 + lxc);
        float4 w4 = *(const float4*)(A + (size_t)(j0 + lwr) * DIMC + c0 + lwc);
        sW[lwc+0][lwr] = w4.x; sW[lwc+1][lwr] = w4.y;
        sW[lwc+2][lwr] = w4.z; sW[lwc+3][lwr] = w4.w;
        __syncthreads();
        #pragma unroll
        for (int kk = 0; kk < 16; ++kk) {
            float4 xf = *(float4*)&sX[kk][tx*4];
            float4 wf = *(float4*)&sW[kk][ty*4];
            float xr[4] = {xf.x, xf.y, xf.z, xf.w};
            float wr[4] = {wf.x, wf.y, wf.z, wf.w};
            #pragma unroll
            for (int r = 0; r < 4; ++r)
                #pragma unroll
                for (int c = 0; c < 4; ++c)
                    acc[r][c] = fmaf(wr[r], xr[c], acc[r][c]);
        }
        __syncthreads();
    }

    const size_t obase = ((size_t)b * DIMC + j0 + ty*4) * HW + n0 + tx*4;
    #pragma unroll
    for (int r = 0; r < 4; ++r)
        *(float4*)(out + obase + (size_t)r * HW) =
            make_float4(acc[r][0], acc[r][1], acc[r][2], acc[r][3]);
}

// ---------------------------------------------------------------------------
// Workspace layout (floats):
//   q     @ 0          16,777,216
//   k     @ 16777216   16,777,216
//   v     @ 33554432   16,777,216
//   rsq   @ 50331648        8,192   (q rows then k rows)
//   Spart @ 50339840    2,097,152   (64 bh x 8 chunks x 64 x 64)
//   attn  @ 52436992      262,144
//   Wp2   @ 52699136    2,097,152
// total 54,796,288 floats = 219.2 MB
// ---------------------------------------------------------------------------
extern "C" void kernel_launch(void* const* d_in, const int* in_sizes, int n_in,
                              void* d_out, int out_size, void* d_ws, size_t ws_size,
                              hipStream_t stream)
{
    const float* x    = (const float*)d_in[0];
    const float* mask = (const float*)d_in[1];
    const float* Wq   = (const float*)d_in[2];
    const float* Wk   = (const float*)d_in[3];
    const float* Wv   = (const float*)d_in[4];
    const float* Wp   = (const float*)d_in[5];
    float* out = (float*)d_out;
    float* ws  = (float*)d_ws;

    float* q     = ws;
    float* k     = ws + 16777216;
    float* v     = ws + 33554432;
    float* rsq   = ws + 50331648;
    float* Spart = ws + 50339840;
    float* attn  = ws + 52436992;
    float* Wp2   = ws + 52699136;

    qkv_gemm    <<<dim3(64, 8, 8), 256, 0, stream>>>(x, mask, Wq, Wk, Wv, q, k, v);
    rowsumsq    <<<8192,           256, 0, stream>>>(q, k, rsq);
    attn_partial<<<dim3(64, 8),    256, 0, stream>>>(q, k, Spart);
    softmax_attn<<<64,              64, 0, stream>>>(Spart, rsq, attn);
    build_wp2   <<<dim3(8, 8, 8),  256, 0, stream>>>(Wp, attn, Wp2);
    gemm_final  <<<dim3(64, 8, 8), 256, 0, stream>>>(Wp2, v, out);
}

// Round 3
// 527.694 us; speedup vs baseline: 1.8339x; 1.8339x over previous
//
#include <hip/hip_runtime.h>
#include <math.h>

#define DIMC 512
#define HW 4096
#define SCALE 0.125f
#define EPSN 1e-12f

typedef __attribute__((ext_vector_type(8))) short bf16x8;
typedef __attribute__((ext_vector_type(4))) float f32x4;

__device__ __forceinline__ unsigned short f2bf(float f) {
    union { float f; unsigned int u; } v; v.f = f;
    unsigned int u = v.u;
    return (unsigned short)((u + 0x7fffu + ((u >> 16) & 1u)) >> 16);
}
__device__ __forceinline__ float bf2f(unsigned short h) {
    union { unsigned int u; float f; } v; v.u = ((unsigned int)h) << 16;
    return v.f;
}

union Pack8 { int4 v; unsigned short u[8]; };

// ---------------------------------------------------------------------------
// P1: convert Wq,Wk,Wv fp32 -> Wb bf16 [3][512][512]
// ---------------------------------------------------------------------------
__global__ __launch_bounds__(256) void convert_w(
    const float* __restrict__ Wq, const float* __restrict__ Wk,
    const float* __restrict__ Wv, unsigned short* __restrict__ Wb)
{
    int i = (blockIdx.x * 256 + threadIdx.x) * 4;   // elem index, 3*262144 total
    int m = i >> 18;                                 // which matrix
    int off = i & 262143;
    const float* s = (m == 0) ? Wq : (m == 1) ? Wk : Wv;
    float4 v4 = *(const float4*)(s + off);
    ushort4 o;
    o.x = f2bf(v4.x); o.y = f2bf(v4.y); o.z = f2bf(v4.z); o.w = f2bf(v4.w);
    *(ushort4*)(Wb + i) = o;
}

// ---------------------------------------------------------------------------
// P2: transpose+convert x[b][c][n] fp32 -> xT[b][n][c] bf16
// ---------------------------------------------------------------------------
__global__ __launch_bounds__(256) void transpose_x(
    const float* __restrict__ x, unsigned short* __restrict__ xT)
{
    const int b  = blockIdx.z;
    const int c0 = blockIdx.y * 64;
    const int n0 = blockIdx.x * 64;
    __shared__ unsigned short sT[64][65];
    const int t = threadIdx.x;
    #pragma unroll
    for (int i = 0; i < 4; ++i) {
        int ch = t + i * 256;                 // 0..1023 (64 rows x 16 float4)
        int r = ch >> 4, col4 = (ch & 15) * 4;
        float4 v4 = *(const float4*)(x + ((size_t)b * DIMC + c0 + r) * HW + n0 + col4);
        sT[r][col4 + 0] = f2bf(v4.x); sT[r][col4 + 1] = f2bf(v4.y);
        sT[r][col4 + 2] = f2bf(v4.z); sT[r][col4 + 3] = f2bf(v4.w);
    }
    __syncthreads();
    #pragma unroll
    for (int i = 0; i < 2; ++i) {
        int ch = t + i * 256;                 // 0..511 (64 n-rows x 8 chunks)
        int n = ch >> 3, cc = (ch & 7) * 8;
        Pack8 pk;
        #pragma unroll
        for (int e = 0; e < 8; ++e) pk.u[e] = sT[cc + e][n];
        *(int4*)(xT + ((size_t)b * HW + n0 + n) * DIMC + c0 + cc) = pk.v;
    }
}

// ---------------------------------------------------------------------------
// P3: transpose vb[b][c][n] bf16 -> vT[b][n][c] bf16
// ---------------------------------------------------------------------------
__global__ __launch_bounds__(256) void transpose_v(
    const unsigned short* __restrict__ vb, unsigned short* __restrict__ vT)
{
    const int b  = blockIdx.z;
    const int c0 = blockIdx.y * 64;
    const int n0 = blockIdx.x * 64;
    __shared__ unsigned short sT[64][65];
    const int t = threadIdx.x;
    #pragma unroll
    for (int i = 0; i < 2; ++i) {
        int ch = t + i * 256;                 // 0..511 (64 rows x 8 chunks of 8)
        int r = ch >> 3, cc = (ch & 7) * 8;
        Pack8 pk;
        pk.v = *(const int4*)(vb + ((size_t)b * DIMC + c0 + r) * HW + n0 + cc);
        #pragma unroll
        for (int e = 0; e < 8; ++e) sT[r][cc + e] = pk.u[e];
    }
    __syncthreads();
    #pragma unroll
    for (int i = 0; i < 2; ++i) {
        int ch = t + i * 256;
        int n = ch >> 3, cc = (ch & 7) * 8;
        Pack8 pk;
        #pragma unroll
        for (int e = 0; e < 8; ++e) pk.u[e] = sT[cc + e][n];
        *(int4*)(vT + ((size_t)b * HW + n0 + n) * DIMC + c0 + cc) = pk.v;
    }
}

// ---------------------------------------------------------------------------
// K1: MFMA QKV projection. out[j][n] = sum_c W[j][c] * x[c][n] (*mask for q,k)
// A = Wb[which] [512j][512c], B = xT[b] [4096n][512c]; both K-contiguous.
// BM=64, BN=128, BK=64, 4 waves (2x2), per-wave 32x64 = 2x4 MFMA tiles.
// LDS rows are 128B (64 bf16); XOR-swizzle byte ^= (row&7)<<4 on both sides.
// ---------------------------------------------------------------------------
__global__ __launch_bounds__(256) void qkv_mfma(
    const unsigned short* __restrict__ Wb, const unsigned short* __restrict__ xT,
    const float* __restrict__ mask,
    unsigned short* __restrict__ q, unsigned short* __restrict__ k,
    unsigned short* __restrict__ vb)
{
    const int which = blockIdx.z >> 3;   // 0=q,1=k,2=v
    const int b     = blockIdx.z & 7;
    const int j0 = blockIdx.y * 64;
    const int n0 = blockIdx.x * 128;
    const unsigned short* A = Wb + (size_t)which * DIMC * DIMC;
    const unsigned short* B = xT + (size_t)b * HW * DIMC;
    unsigned short* outp = (which == 0) ? q : (which == 1) ? k : vb;

    __shared__ unsigned short sA[64 * 64];
    __shared__ unsigned short sB[128 * 64];

    const int t = threadIdx.x, lane = t & 63, w = t >> 6;
    const int wm = w >> 1, wn = w & 1;

    f32x4 zero = {0.f, 0.f, 0.f, 0.f};
    f32x4 acc[2][4];
    #pragma unroll
    for (int m = 0; m < 2; ++m)
        #pragma unroll
        for (int n = 0; n < 4; ++n) acc[m][n] = zero;

    int offA[2], offB[4];
    const unsigned short* gA[2];
    const unsigned short* gB[4];
    #pragma unroll
    for (int i = 0; i < 2; ++i) {
        int ch = t + i * 256, r = ch >> 3, sl = ch & 7;
        offA[i] = r * 128 + ((sl ^ (r & 7)) << 4);
        gA[i] = A + (size_t)(j0 + r) * DIMC + sl * 8;
    }
    #pragma unroll
    for (int i = 0; i < 4; ++i) {
        int ch = t + i * 256, r = ch >> 3, sl = ch & 7;
        offB[i] = r * 128 + ((sl ^ (r & 7)) << 4);
        gB[i] = B + (size_t)(n0 + r) * DIMC + sl * 8;
    }

    int4 ra[2], rb[4];
    #pragma unroll
    for (int i = 0; i < 2; ++i) ra[i] = *(const int4*)(gA[i]);
    #pragma unroll
    for (int i = 0; i < 4; ++i) rb[i] = *(const int4*)(gB[i]);

    for (int c0 = 0; c0 < DIMC; c0 += 64) {
        __syncthreads();
        #pragma unroll
        for (int i = 0; i < 2; ++i) *(int4*)((char*)sA + offA[i]) = ra[i];
        #pragma unroll
        for (int i = 0; i < 4; ++i) *(int4*)((char*)sB + offB[i]) = rb[i];
        __syncthreads();
        if (c0 + 64 < DIMC) {
            #pragma unroll
            for (int i = 0; i < 2; ++i) ra[i] = *(const int4*)(gA[i] + c0 + 64);
            #pragma unroll
            for (int i = 0; i < 4; ++i) rb[i] = *(const int4*)(gB[i] + c0 + 64);
        }
        #pragma unroll
        for (int s = 0; s < 2; ++s) {
            bf16x8 af[2], bfr[4];
            #pragma unroll
            for (int m = 0; m < 2; ++m) {
                int r = wm * 32 + m * 16 + (lane & 15);
                int byte = r * 128 + s * 64 + ((lane >> 4) << 4);
                byte ^= (r & 7) << 4;
                af[m] = *(const bf16x8*)((const char*)sA + byte);
            }
            #pragma unroll
            for (int n = 0; n < 4; ++n) {
                int r = wn * 64 + n * 16 + (lane & 15);
                int byte = r * 128 + s * 64 + ((lane >> 4) << 4);
                byte ^= (r & 7) << 4;
                bfr[n] = *(const bf16x8*)((const char*)sB + byte);
            }
            #pragma unroll
            for (int m = 0; m < 2; ++m)
                #pragma unroll
                for (int n = 0; n < 4; ++n)
                    acc[m][n] = __builtin_amdgcn_mfma_f32_16x16x32_bf16(
                        af[m], bfr[n], acc[m][n], 0, 0, 0);
        }
    }

    float mv[4];
    #pragma unroll
    for (int n = 0; n < 4; ++n)
        mv[n] = (which < 2)
              ? mask[(size_t)b * HW + n0 + wn * 64 + n * 16 + (lane & 15)]
              : 1.0f;
    #pragma unroll
    for (int m = 0; m < 2; ++m)
        #pragma unroll
        for (int r4 = 0; r4 < 4; ++r4) {
            int j = j0 + wm * 32 + m * 16 + ((lane >> 4) << 2) + r4;
            size_t rowbase = ((size_t)b * DIMC + j) * HW + n0 + wn * 64 + (lane & 15);
            #pragma unroll
            for (int n = 0; n < 4; ++n)
                outp[rowbase + n * 16] = f2bf(acc[m][n][r4] * mv[n]);
        }
}

// ---------------------------------------------------------------------------
// K2: per-row sumsq over bf16 q,k -> rsq
// ---------------------------------------------------------------------------
__global__ __launch_bounds__(256) void rowsumsq_bf16(
    const unsigned short* __restrict__ q, const unsigned short* __restrict__ k,
    float* __restrict__ rsq)
{
    const int row = blockIdx.x;   // 0..8191
    const unsigned short* p = (row < 4096) ? (q + (size_t)row * HW)
                                           : (k + (size_t)(row - 4096) * HW);
    float s = 0.f;
    for (int i = threadIdx.x * 8; i < HW; i += 2048) {
        Pack8 pk; pk.v = *(const int4*)(p + i);
        #pragma unroll
        for (int e = 0; e < 8; ++e) {
            float f = bf2f(pk.u[e]);
            s = fmaf(f, f, s);
        }
    }
    #pragma unroll
    for (int o = 32; o > 0; o >>= 1) s += __shfl_down(s, o, 64);
    __shared__ float red[4];
    if ((threadIdx.x & 63) == 0) red[threadIdx.x >> 6] = s;
    __syncthreads();
    if (threadIdx.x == 0) {
        float tot = red[0] + red[1] + red[2] + red[3];
        rsq[row] = 1.0f / fmaxf(sqrtf(tot), EPSN);
    }
}

// ---------------------------------------------------------------------------
// K3: MFMA attention logits (NT GEMM, no transposes needed).
// Spart[bh][chunk][r][c] = sum_{n in chunk} q[r][n]*k[c][n], chunk=512 wide.
// Per block: 64x64 output, 4 waves 2x2 (each 32x32 = 2x2 tiles), BKn=64.
// ---------------------------------------------------------------------------
__global__ __launch_bounds__(256) void attn_mfma(
    const unsigned short* __restrict__ q, const unsigned short* __restrict__ k,
    float* __restrict__ Spart)
{
    const int bh = blockIdx.x;     // b*8+h ; row base = bh*64
    const int chunk = blockIdx.y;  // 0..7
    const unsigned short* Q = q + (size_t)bh * 64 * HW;
    const unsigned short* K = k + (size_t)bh * 64 * HW;

    __shared__ unsigned short sQ[64 * 64];
    __shared__ unsigned short sK[64 * 64];

    const int t = threadIdx.x, lane = t & 63, w = t >> 6;
    const int wm = w >> 1, wn = w & 1;

    f32x4 zero = {0.f, 0.f, 0.f, 0.f};
    f32x4 acc[2][2];
    #pragma unroll
    for (int m = 0; m < 2; ++m)
        #pragma unroll
        for (int n = 0; n < 2; ++n) acc[m][n] = zero;

    int offs[2];
    const unsigned short* gQ[2];
    const unsigned short* gK[2];
    const int nb = chunk * 512;
    #pragma unroll
    for (int i = 0; i < 2; ++i) {
        int ch = t + i * 256, r = ch >> 3, sl = ch & 7;
        offs[i] = r * 128 + ((sl ^ (r & 7)) << 4);
        gQ[i] = Q + (size_t)r * HW + nb + sl * 8;
        gK[i] = K + (size_t)r * HW + nb + sl * 8;
    }

    int4 ra[2], rb[2];
    #pragma unroll
    for (int i = 0; i < 2; ++i) { ra[i] = *(const int4*)(gQ[i]); rb[i] = *(const int4*)(gK[i]); }

    for (int it = 0; it < 8; ++it) {
        __syncthreads();
        #pragma unroll
        for (int i = 0; i < 2; ++i) {
            *(int4*)((char*)sQ + offs[i]) = ra[i];
            *(int4*)((char*)sK + offs[i]) = rb[i];
        }
        __syncthreads();
        if (it < 7) {
            #pragma unroll
            for (int i = 0; i < 2; ++i) {
                ra[i] = *(const int4*)(gQ[i] + (it + 1) * 64);
                rb[i] = *(const int4*)(gK[i] + (it + 1) * 64);
            }
        }
        #pragma unroll
        for (int s = 0; s < 2; ++s) {
            bf16x8 aq[2], bk[2];
            #pragma unroll
            for (int m = 0; m < 2; ++m) {
                int r = wm * 32 + m * 16 + (lane & 15);
                int byte = r * 128 + s * 64 + ((lane >> 4) << 4);
                byte ^= (r & 7) << 4;
                aq[m] = *(const bf16x8*)((const char*)sQ + byte);
            }
            #pragma unroll
            for (int n = 0; n < 2; ++n) {
                int r = wn * 32 + n * 16 + (lane & 15);
                int byte = r * 128 + s * 64 + ((lane >> 4) << 4);
                byte ^= (r & 7) << 4;
                bk[n] = *(const bf16x8*)((const char*)sK + byte);
            }
            #pragma unroll
            for (int m = 0; m < 2; ++m)
                #pragma unroll
                for (int n = 0; n < 2; ++n)
                    acc[m][n] = __builtin_amdgcn_mfma_f32_16x16x32_bf16(
                        aq[m], bk[n], acc[m][n], 0, 0, 0);
        }
    }

    float* Sp = Spart + ((size_t)(bh * 8 + chunk) << 12);
    #pragma unroll
    for (int m = 0; m < 2; ++m)
        #pragma unroll
        for (int n = 0; n < 2; ++n)
            #pragma unroll
            for (int r4 = 0; r4 < 4; ++r4) {
                int r = wm * 32 + m * 16 + ((lane >> 4) << 2) + r4;
                int c = wn * 32 + n * 16 + (lane & 15);
                Sp[r * 64 + c] = acc[m][n][r4];
            }
}

// ---------------------------------------------------------------------------
// K4: combine partials + normalization + scale + row softmax (fp32)
// ---------------------------------------------------------------------------
__global__ __launch_bounds__(64) void softmax_attn(
    const float* __restrict__ Spart, const float* __restrict__ rsq,
    float* __restrict__ attn)
{
    const int bh = blockIdx.x;
    const int b = bh >> 3, h = bh & 7;
    const int r = threadIdx.x;
    const float rq = rsq[b * DIMC + h * 64 + r];
    const float* Sp = Spart + ((size_t)(bh * 8) << 12) + r * 64;

    float row[64];
    #pragma unroll 8
    for (int c = 0; c < 64; ++c) {
        float s = 0.f;
        #pragma unroll
        for (int ch = 0; ch < 8; ++ch) s += Sp[((size_t)ch << 12) + c];
        row[c] = s * SCALE * rq * rsq[4096 + b * DIMC + h * 64 + c];
    }
    float mx = -1e30f;
    #pragma unroll 8
    for (int c = 0; c < 64; ++c) mx = fmaxf(mx, row[c]);
    float sum = 0.f;
    #pragma unroll 8
    for (int c = 0; c < 64; ++c) { row[c] = __expf(row[c] - mx); sum += row[c]; }
    const float inv = 1.0f / sum;
    float* A = attn + ((size_t)bh << 12) + r * 64;
    #pragma unroll 8
    for (int c = 0; c < 64; ++c) A[c] = row[c] * inv;
}

// ---------------------------------------------------------------------------
// K5: fold Wp through attn -> Wp2b bf16 [b][j][c]
// ---------------------------------------------------------------------------
__global__ __launch_bounds__(256) void build_wp2(
    const float* __restrict__ Wp, const float* __restrict__ attn,
    unsigned short* __restrict__ Wp2b)
{
    const int jt = blockIdx.x;
    const int h  = blockIdx.y;
    const int b  = blockIdx.z;

    __shared__ float sA[64][64];   // attn[c][d]
    __shared__ float sW[64][64];   // Wp [c][j] transposed

    const int t = threadIdx.x;
    {
        const float* A = attn + ((size_t)(b * 8 + h) << 12);
        for (int i = t * 4; i < 4096; i += 1024)
            *(float4*)&sA[0][i] = *(const float4*)(A + i);
    }
    {
        const int j  = t >> 2;
        const int c0 = (t & 3) * 16;
        #pragma unroll
        for (int i = 0; i < 4; ++i) {
            float4 w4 = *(const float4*)(Wp + (size_t)(jt * 64 + j) * DIMC + h * 64 + c0 + i * 4);
            sW[c0 + i * 4 + 0][j] = w4.x; sW[c0 + i * 4 + 1][j] = w4.y;
            sW[c0 + i * 4 + 2][j] = w4.z; sW[c0 + i * 4 + 3][j] = w4.w;
        }
    }
    __syncthreads();

    const int tx = t & 15, ty = t >> 4;
    float acc[4][4] = {};
    #pragma unroll 16
    for (int c = 0; c < 64; ++c) {
        float wf[4], af[4];
        #pragma unroll
        for (int i = 0; i < 4; ++i) { wf[i] = sW[c][ty * 4 + i]; af[i] = sA[c][tx * 4 + i]; }
        #pragma unroll
        for (int r = 0; r < 4; ++r)
            #pragma unroll
            for (int cc = 0; cc < 4; ++cc)
                acc[r][cc] = fmaf(wf[r], af[cc], acc[r][cc]);
    }

    unsigned short* O = Wp2b + ((size_t)b * DIMC + jt * 64 + ty * 4) * DIMC + h * 64 + tx * 4;
    #pragma unroll
    for (int r = 0; r < 4; ++r) {
        ushort4 o4;
        o4.x = f2bf(acc[r][0]); o4.y = f2bf(acc[r][1]);
        o4.z = f2bf(acc[r][2]); o4.w = f2bf(acc[r][3]);
        *(ushort4*)(O + (size_t)r * DIMC) = o4;
    }
}

// ---------------------------------------------------------------------------
// K6: final MFMA GEMM: out[b][j][n] = sum_c Wp2b[b][j][c] * vT[b][n][c]
// Same structure as qkv_mfma, fp32 output straight into d_out.
// ---------------------------------------------------------------------------
__global__ __launch_bounds__(256) void final_mfma(
    const unsigned short* __restrict__ Wp2b, const unsigned short* __restrict__ vT,
    float* __restrict__ out)
{
    const int b  = blockIdx.z;
    const int j0 = blockIdx.y * 64;
    const int n0 = blockIdx.x * 128;
    const unsigned short* A = Wp2b + (size_t)b * DIMC * DIMC;
    const unsigned short* B = vT + (size_t)b * HW * DIMC;

    __shared__ unsigned short sA[64 * 64];
    __shared__ unsigned short sB[128 * 64];

    const int t = threadIdx.x, lane = t & 63, w = t >> 6;
    const int wm = w >> 1, wn = w & 1;

    f32x4 zero = {0.f, 0.f, 0.f, 0.f};
    f32x4 acc[2][4];
    #pragma unroll
    for (int m = 0; m < 2; ++m)
        #pragma unroll
        for (int n = 0; n < 4; ++n) acc[m][n] = zero;

    int offA[2], offB[4];
    const unsigned short* gA[2];
    const unsigned short* gB[4];
    #pragma unroll
    for (int i = 0; i < 2; ++i) {
        int ch = t + i * 256, r = ch >> 3, sl = ch & 7;
        offA[i] = r * 128 + ((sl ^ (r & 7)) << 4);
        gA[i] = A + (size_t)(j0 + r) * DIMC + sl * 8;
    }
    #pragma unroll
    for (int i = 0; i < 4; ++i) {
        int ch = t + i * 256, r = ch >> 3, sl = ch & 7;
        offB[i] = r * 128 + ((sl ^ (r & 7)) << 4);
        gB[i] = B + (size_t)(n0 + r) * DIMC + sl * 8;
    }

    int4 ra[2], rb[4];
    #pragma unroll
    for (int i = 0; i < 2; ++i) ra[i] = *(const int4*)(gA[i]);
    #pragma unroll
    for (int i = 0; i < 4; ++i) rb[i] = *(const int4*)(gB[i]);

    for (int c0 = 0; c0 < DIMC; c0 += 64) {
        __syncthreads();
        #pragma unroll
        for (int i = 0; i < 2; ++i) *(int4*)((char*)sA + offA[i]) = ra[i];
        #pragma unroll
        for (int i = 0; i < 4; ++i) *(int4*)((char*)sB + offB[i]) = rb[i];
        __syncthreads();
        if (c0 + 64 < DIMC) {
            #pragma unroll
            for (int i = 0; i < 2; ++i) ra[i] = *(const int4*)(gA[i] + c0 + 64);
            #pragma unroll
            for (int i = 0; i < 4; ++i) rb[i] = *(const int4*)(gB[i] + c0 + 64);
        }
        #pragma unroll
        for (int s = 0; s < 2; ++s) {
            bf16x8 af[2], bfr[4];
            #pragma unroll
            for (int m = 0; m < 2; ++m) {
                int r = wm * 32 + m * 16 + (lane & 15);
                int byte = r * 128 + s * 64 + ((lane >> 4) << 4);
                byte ^= (r & 7) << 4;
                af[m] = *(const bf16x8*)((const char*)sA + byte);
            }
            #pragma unroll
            for (int n = 0; n < 4; ++n) {
                int r = wn * 64 + n * 16 + (lane & 15);
                int byte = r * 128 + s * 64 + ((lane >> 4) << 4);
                byte ^= (r & 7) << 4;
                bfr[n] = *(const bf16x8*)((const char*)sB + byte);
            }
            #pragma unroll
            for (int m = 0; m < 2; ++m)
                #pragma unroll
                for (int n = 0; n < 4; ++n)
                    acc[m][n] = __builtin_amdgcn_mfma_f32_16x16x32_bf16(
                        af[m], bfr[n], acc[m][n], 0, 0, 0);
        }
    }

    #pragma unroll
    for (int m = 0; m < 2; ++m)
        #pragma unroll
        for (int r4 = 0; r4 < 4; ++r4) {
            int j = j0 + wm * 32 + m * 16 + ((lane >> 4) << 2) + r4;
            size_t rowbase = ((size_t)b * DIMC + j) * HW + n0 + wn * 64 + (lane & 15);
            #pragma unroll
            for (int n = 0; n < 4; ++n)
                out[rowbase + n * 16] = acc[m][n][r4];
        }
}

// ---------------------------------------------------------------------------
// Workspace (bytes):
//   xT    @ 0           33,554,432
//   q     @ 33554432    33,554,432
//   k     @ 67108864    33,554,432
//   vb    @ 100663296   33,554,432
//   vT    @ 134217728   33,554,432
//   Wb    @ 167772160    1,572,864
//   Wp2b  @ 169345024    4,194,304
//   rsq   @ 173539328       32,768
//   Spart @ 173572096    8,388,608
//   attn  @ 181960704    1,048,576
//   end 183,009,280  (< prior 219 MB usage)
// ---------------------------------------------------------------------------
extern "C" void kernel_launch(void* const* d_in, const int* in_sizes, int n_in,
                              void* d_out, int out_size, void* d_ws, size_t ws_size,
                              hipStream_t stream)
{
    const float* x    = (const float*)d_in[0];
    const float* mask = (const float*)d_in[1];
    const float* Wq   = (const float*)d_in[2];
    const float* Wk   = (const float*)d_in[3];
    const float* Wv   = (const float*)d_in[4];
    const float* Wp   = (const float*)d_in[5];
    float* out = (float*)d_out;
    char* wsb = (char*)d_ws;

    unsigned short* xT   = (unsigned short*)(wsb + 0);
    unsigned short* q    = (unsigned short*)(wsb + 33554432);
    unsigned short* k    = (unsigned short*)(wsb + 67108864);
    unsigned short* vb   = (unsigned short*)(wsb + 100663296);
    unsigned short* vT   = (unsigned short*)(wsb + 134217728);
    unsigned short* Wb   = (unsigned short*)(wsb + 167772160);
    unsigned short* Wp2b = (unsigned short*)(wsb + 169345024);
    float* rsq   = (float*)(wsb + 173539328);
    float* Spart = (float*)(wsb + 173572096);
    float* attn  = (float*)(wsb + 181960704);

    convert_w    <<<768,              256, 0, stream>>>(Wq, Wk, Wv, Wb);
    transpose_x  <<<dim3(64, 8, 8),   256, 0, stream>>>(x, xT);
    qkv_mfma     <<<dim3(32, 8, 24),  256, 0, stream>>>(Wb, xT, mask, q, k, vb);
    transpose_v  <<<dim3(64, 8, 8),   256, 0, stream>>>(vb, vT);
    rowsumsq_bf16<<<8192,             256, 0, stream>>>(q, k, rsq);
    attn_mfma    <<<dim3(64, 8),      256, 0, stream>>>(q, k, Spart);
    softmax_attn <<<64,                64, 0, stream>>>(Spart, rsq, attn);
    build_wp2    <<<dim3(8, 8, 8),    256, 0, stream>>>(Wp, attn, Wp2b);
    final_mfma   <<<dim3(32, 8, 8),   256, 0, stream>>>(Wp2b, vT, out);
}

// Round 4
// 433.097 us; speedup vs baseline: 2.2345x; 1.2184x over previous
//
#include <hip/hip_runtime.h>
#include <math.h>

#define DIMC 512
#define HW 4096
#define SCALE 0.125f
#define EPSN 1e-12f

typedef __attribute__((ext_vector_type(8))) short bf16x8;
typedef __attribute__((ext_vector_type(4))) float f32x4;

__device__ __forceinline__ unsigned short f2bf(float f) {
    union { float f; unsigned int u; } v; v.f = f;
    unsigned int u = v.u;
    return (unsigned short)((u + 0x7fffu + ((u >> 16) & 1u)) >> 16);
}
__device__ __forceinline__ float bf2f(unsigned short h) {
    union { unsigned int u; float f; } v; v.u = ((unsigned int)h) << 16;
    return v.f;
}

union Pack8 { int4 v; unsigned short u[8]; };

// ---------------------------------------------------------------------------
// P1: convert Wq,Wk,Wv fp32 -> Wb bf16 [3][512][512]
// ---------------------------------------------------------------------------
__global__ __launch_bounds__(256) void convert_w(
    const float* __restrict__ Wq, const float* __restrict__ Wk,
    const float* __restrict__ Wv, unsigned short* __restrict__ Wb)
{
    int i = (blockIdx.x * 256 + threadIdx.x) * 4;
    int m = i >> 18;
    int off = i & 262143;
    const float* s = (m == 0) ? Wq : (m == 1) ? Wk : Wv;
    float4 v4 = *(const float4*)(s + off);
    ushort4 o;
    o.x = f2bf(v4.x); o.y = f2bf(v4.y); o.z = f2bf(v4.z); o.w = f2bf(v4.w);
    *(ushort4*)(Wb + i) = o;
}

// ---------------------------------------------------------------------------
// P2: transpose+convert x[b][c][n] fp32 -> xT[b][n][c] bf16
// ---------------------------------------------------------------------------
__global__ __launch_bounds__(256) void transpose_x(
    const float* __restrict__ x, unsigned short* __restrict__ xT)
{
    const int b  = blockIdx.z;
    const int c0 = blockIdx.y * 64;
    const int n0 = blockIdx.x * 64;
    __shared__ unsigned short sT[64][65];
    const int t = threadIdx.x;
    #pragma unroll
    for (int i = 0; i < 4; ++i) {
        int ch = t + i * 256;
        int r = ch >> 4, col4 = (ch & 15) * 4;
        float4 v4 = *(const float4*)(x + ((size_t)b * DIMC + c0 + r) * HW + n0 + col4);
        sT[r][col4 + 0] = f2bf(v4.x); sT[r][col4 + 1] = f2bf(v4.y);
        sT[r][col4 + 2] = f2bf(v4.z); sT[r][col4 + 3] = f2bf(v4.w);
    }
    __syncthreads();
    #pragma unroll
    for (int i = 0; i < 2; ++i) {
        int ch = t + i * 256;
        int n = ch >> 3, cc = (ch & 7) * 8;
        Pack8 pk;
        #pragma unroll
        for (int e = 0; e < 8; ++e) pk.u[e] = sT[cc + e][n];
        *(int4*)(xT + ((size_t)b * HW + n0 + n) * DIMC + c0 + cc) = pk.v;
    }
}

// ---------------------------------------------------------------------------
// K1: fused MFMA QKV projection.
//   q[b][j][n] = mask[b][n] * sum_c Wq[j][c]*x[c][n]   (bf16 out, [j][n])
//   k          = same with Wk
//   vT[b][n][j] = sum_c Wv[j][c]*x[c][n]               (bf16 out, TRANSPOSED)
// One block: 64(j) x 128(n), BK=64, 4 waves (2x2), 3 accumulator sets over a
// shared B tile. Epilogue: LDS-staged fully-coalesced int4 stores (fixes the
// R3 8x write amplification); v staged transposed; per-row sumsq of masked
// q,k shfl-reduced and atomicAdd'ed into sumsq[2][8][512].
// ---------------------------------------------------------------------------
__global__ __launch_bounds__(256, 2) void qkv_mfma(
    const unsigned short* __restrict__ Wb, const unsigned short* __restrict__ xT,
    const float* __restrict__ mask,
    unsigned short* __restrict__ q, unsigned short* __restrict__ k,
    unsigned short* __restrict__ vT, float* __restrict__ sumsq)
{
    const int b  = blockIdx.z;
    const int j0 = blockIdx.y * 64;
    const int n0 = blockIdx.x * 128;
    const unsigned short* Aq = Wb;
    const unsigned short* Ak = Wb + 262144;
    const unsigned short* Av = Wb + 524288;
    const unsigned short* B  = xT + (size_t)b * HW * DIMC;

    // 0..8191 sAq | 8192..16383 sAk | 16384..24575 sAv | 24576..40959 sB
    __shared__ __align__(16) char sm[40960];

    const int t = threadIdx.x, lane = t & 63, w = t >> 6;
    const int wm = w >> 1, wn = w & 1;

    f32x4 zero = {0.f, 0.f, 0.f, 0.f};
    f32x4 accQ[2][4], accK[2][4], accV[2][4];
    #pragma unroll
    for (int m = 0; m < 2; ++m)
        #pragma unroll
        for (int n = 0; n < 4; ++n) { accQ[m][n] = zero; accK[m][n] = zero; accV[m][n] = zero; }

    int offA[2], offB[4];
    const unsigned short *gAq[2], *gAk[2], *gAv[2], *gB[4];
    #pragma unroll
    for (int i = 0; i < 2; ++i) {
        int ch = t + i * 256, r = ch >> 3, sl = ch & 7;
        offA[i] = r * 128 + ((sl ^ (r & 7)) << 4);
        size_t go = (size_t)(j0 + r) * DIMC + sl * 8;
        gAq[i] = Aq + go; gAk[i] = Ak + go; gAv[i] = Av + go;
    }
    #pragma unroll
    for (int i = 0; i < 4; ++i) {
        int ch = t + i * 256, r = ch >> 3, sl = ch & 7;
        offB[i] = r * 128 + ((sl ^ (r & 7)) << 4);
        gB[i] = B + (size_t)(n0 + r) * DIMC + sl * 8;
    }

    int4 rq[2], rk[2], rv[2], rb[4];
    #pragma unroll
    for (int i = 0; i < 2; ++i) {
        rq[i] = *(const int4*)(gAq[i]);
        rk[i] = *(const int4*)(gAk[i]);
        rv[i] = *(const int4*)(gAv[i]);
    }
    #pragma unroll
    for (int i = 0; i < 4; ++i) rb[i] = *(const int4*)(gB[i]);

    for (int c0 = 0; c0 < DIMC; c0 += 64) {
        __syncthreads();
        #pragma unroll
        for (int i = 0; i < 2; ++i) {
            *(int4*)(sm + offA[i])         = rq[i];
            *(int4*)(sm + 8192  + offA[i]) = rk[i];
            *(int4*)(sm + 16384 + offA[i]) = rv[i];
        }
        #pragma unroll
        for (int i = 0; i < 4; ++i) *(int4*)(sm + 24576 + offB[i]) = rb[i];
        __syncthreads();
        if (c0 + 64 < DIMC) {
            #pragma unroll
            for (int i = 0; i < 2; ++i) {
                rq[i] = *(const int4*)(gAq[i] + c0 + 64);
                rk[i] = *(const int4*)(gAk[i] + c0 + 64);
                rv[i] = *(const int4*)(gAv[i] + c0 + 64);
            }
            #pragma unroll
            for (int i = 0; i < 4; ++i) rb[i] = *(const int4*)(gB[i] + c0 + 64);
        }
        #pragma unroll
        for (int s = 0; s < 2; ++s) {
            bf16x8 aq[2], ak[2], av[2], bfr[4];
            #pragma unroll
            for (int m = 0; m < 2; ++m) {
                int r = wm * 32 + m * 16 + (lane & 15);
                int byte = r * 128 + s * 64 + ((lane >> 4) << 4);
                byte ^= (r & 7) << 4;
                aq[m] = *(const bf16x8*)(sm + byte);
                ak[m] = *(const bf16x8*)(sm + 8192 + byte);
                av[m] = *(const bf16x8*)(sm + 16384 + byte);
            }
            #pragma unroll
            for (int n = 0; n < 4; ++n) {
                int r = wn * 64 + n * 16 + (lane & 15);
                int byte = r * 128 + s * 64 + ((lane >> 4) << 4);
                byte ^= (r & 7) << 4;
                bfr[n] = *(const bf16x8*)(sm + 24576 + byte);
            }
            #pragma unroll
            for (int m = 0; m < 2; ++m)
                #pragma unroll
                for (int n = 0; n < 4; ++n) {
                    accQ[m][n] = __builtin_amdgcn_mfma_f32_16x16x32_bf16(aq[m], bfr[n], accQ[m][n], 0, 0, 0);
                    accK[m][n] = __builtin_amdgcn_mfma_f32_16x16x32_bf16(ak[m], bfr[n], accK[m][n], 0, 0, 0);
                    accV[m][n] = __builtin_amdgcn_mfma_f32_16x16x32_bf16(av[m], bfr[n], accV[m][n], 0, 0, 0);
                }
        }
    }

    // mask per column fragment
    float mv[4];
    #pragma unroll
    for (int n = 0; n < 4; ++n)
        mv[n] = mask[(size_t)b * HW + n0 + wn * 64 + n * 16 + (lane & 15)];

    // fused sumsq of masked q,k: reduce over the 16 lanes sharing a row,
    // one atomicAdd per (row, 64-col slice)
    #pragma unroll
    for (int X = 0; X < 2; ++X) {
        #pragma unroll
        for (int m = 0; m < 2; ++m)
            #pragma unroll
            for (int r4 = 0; r4 < 4; ++r4) {
                float s = 0.f;
                #pragma unroll
                for (int n = 0; n < 4; ++n) {
                    float val = (X ? accK[m][n][r4] : accQ[m][n][r4]) * mv[n];
                    s = fmaf(val, val, s);
                }
                s += __shfl_xor(s, 8, 16);
                s += __shfl_xor(s, 4, 16);
                s += __shfl_xor(s, 2, 16);
                s += __shfl_xor(s, 1, 16);
                if ((lane & 15) == 0) {
                    int j = j0 + wm * 32 + m * 16 + ((lane >> 4) << 2) + r4;
                    atomicAdd(&sumsq[X * 4096 + b * DIMC + j], s);
                }
            }
    }

    // ---- epilogue: LDS-staged coalesced stores ----
    unsigned short* st = (unsigned short*)sm;

    // q tile [64j][128n], stride 136 shorts (272B)
    __syncthreads();
    #pragma unroll
    for (int m = 0; m < 2; ++m)
        #pragma unroll
        for (int n = 0; n < 4; ++n)
            #pragma unroll
            for (int r4 = 0; r4 < 4; ++r4) {
                int jl = wm * 32 + m * 16 + ((lane >> 4) << 2) + r4;
                int nl = wn * 64 + n * 16 + (lane & 15);
                st[jl * 136 + nl] = f2bf(accQ[m][n][r4] * mv[n]);
            }
    __syncthreads();
    #pragma unroll
    for (int it = 0; it < 4; ++it) {
        int idx = t + it * 256, jl = idx >> 4, l16 = idx & 15;
        int4 pv = *(int4*)(sm + jl * 272 + l16 * 16);
        *(int4*)(q + ((size_t)b * DIMC + j0 + jl) * HW + n0 + l16 * 8) = pv;
    }

    // k tile
    __syncthreads();
    #pragma unroll
    for (int m = 0; m < 2; ++m)
        #pragma unroll
        for (int n = 0; n < 4; ++n)
            #pragma unroll
            for (int r4 = 0; r4 < 4; ++r4) {
                int jl = wm * 32 + m * 16 + ((lane >> 4) << 2) + r4;
                int nl = wn * 64 + n * 16 + (lane & 15);
                st[jl * 136 + nl] = f2bf(accK[m][n][r4] * mv[n]);
            }
    __syncthreads();
    #pragma unroll
    for (int it = 0; it < 4; ++it) {
        int idx = t + it * 256, jl = idx >> 4, l16 = idx & 15;
        int4 pv = *(int4*)(sm + jl * 272 + l16 * 16);
        *(int4*)(k + ((size_t)b * DIMC + j0 + jl) * HW + n0 + l16 * 8) = pv;
    }

    // v transposed tile [128n][64j], stride 72 shorts (144B)
    __syncthreads();
    #pragma unroll
    for (int m = 0; m < 2; ++m)
        #pragma unroll
        for (int n = 0; n < 4; ++n)
            #pragma unroll
            for (int r4 = 0; r4 < 4; ++r4) {
                int jl = wm * 32 + m * 16 + ((lane >> 4) << 2) + r4;
                int nl = wn * 64 + n * 16 + (lane & 15);
                st[nl * 72 + jl] = f2bf(accV[m][n][r4]);
            }
    __syncthreads();
    #pragma unroll
    for (int it = 0; it < 4; ++it) {
        int idx = t + it * 256, nl = idx >> 3, c8 = idx & 7;
        int4 pv = *(int4*)(sm + nl * 144 + c8 * 16);
        *(int4*)(vT + ((size_t)b * HW + n0 + nl) * DIMC + j0 + c8 * 8) = pv;
    }
}

// ---------------------------------------------------------------------------
// K3: MFMA attention logits (NT GEMM).
// Spart[bh][chunk][r][c] = sum_{n in chunk} q[r][n]*k[c][n], chunk=512 wide.
// ---------------------------------------------------------------------------
__global__ __launch_bounds__(256) void attn_mfma(
    const unsigned short* __restrict__ q, const unsigned short* __restrict__ k,
    float* __restrict__ Spart)
{
    const int bh = blockIdx.x;
    const int chunk = blockIdx.y;
    const unsigned short* Q = q + (size_t)bh * 64 * HW;
    const unsigned short* K = k + (size_t)bh * 64 * HW;

    __shared__ unsigned short sQ[64 * 64];
    __shared__ unsigned short sK[64 * 64];

    const int t = threadIdx.x, lane = t & 63, w = t >> 6;
    const int wm = w >> 1, wn = w & 1;

    f32x4 zero = {0.f, 0.f, 0.f, 0.f};
    f32x4 acc[2][2];
    #pragma unroll
    for (int m = 0; m < 2; ++m)
        #pragma unroll
        for (int n = 0; n < 2; ++n) acc[m][n] = zero;

    int offs[2];
    const unsigned short* gQ[2];
    const unsigned short* gK[2];
    const int nb = chunk * 512;
    #pragma unroll
    for (int i = 0; i < 2; ++i) {
        int ch = t + i * 256, r = ch >> 3, sl = ch & 7;
        offs[i] = r * 128 + ((sl ^ (r & 7)) << 4);
        gQ[i] = Q + (size_t)r * HW + nb + sl * 8;
        gK[i] = K + (size_t)r * HW + nb + sl * 8;
    }

    int4 ra[2], rb[2];
    #pragma unroll
    for (int i = 0; i < 2; ++i) { ra[i] = *(const int4*)(gQ[i]); rb[i] = *(const int4*)(gK[i]); }

    for (int it = 0; it < 8; ++it) {
        __syncthreads();
        #pragma unroll
        for (int i = 0; i < 2; ++i) {
            *(int4*)((char*)sQ + offs[i]) = ra[i];
            *(int4*)((char*)sK + offs[i]) = rb[i];
        }
        __syncthreads();
        if (it < 7) {
            #pragma unroll
            for (int i = 0; i < 2; ++i) {
                ra[i] = *(const int4*)(gQ[i] + (it + 1) * 64);
                rb[i] = *(const int4*)(gK[i] + (it + 1) * 64);
            }
        }
        #pragma unroll
        for (int s = 0; s < 2; ++s) {
            bf16x8 aq[2], bk[2];
            #pragma unroll
            for (int m = 0; m < 2; ++m) {
                int r = wm * 32 + m * 16 + (lane & 15);
                int byte = r * 128 + s * 64 + ((lane >> 4) << 4);
                byte ^= (r & 7) << 4;
                aq[m] = *(const bf16x8*)((const char*)sQ + byte);
            }
            #pragma unroll
            for (int n = 0; n < 2; ++n) {
                int r = wn * 32 + n * 16 + (lane & 15);
                int byte = r * 128 + s * 64 + ((lane >> 4) << 4);
                byte ^= (r & 7) << 4;
                bk[n] = *(const bf16x8*)((const char*)sK + byte);
            }
            #pragma unroll
            for (int m = 0; m < 2; ++m)
                #pragma unroll
                for (int n = 0; n < 2; ++n)
                    acc[m][n] = __builtin_amdgcn_mfma_f32_16x16x32_bf16(
                        aq[m], bk[n], acc[m][n], 0, 0, 0);
        }
    }

    float* Sp = Spart + ((size_t)(bh * 8 + chunk) << 12);
    #pragma unroll
    for (int m = 0; m < 2; ++m)
        #pragma unroll
        for (int n = 0; n < 2; ++n)
            #pragma unroll
            for (int r4 = 0; r4 < 4; ++r4) {
                int r = wm * 32 + m * 16 + ((lane >> 4) << 2) + r4;
                int c = wn * 32 + n * 16 + (lane & 15);
                Sp[r * 64 + c] = acc[m][n][r4];
            }
}

// ---------------------------------------------------------------------------
// K4: combine partials + inline rsq from sumsq + scale + row softmax (fp32)
// ---------------------------------------------------------------------------
__global__ __launch_bounds__(64) void softmax_attn(
    const float* __restrict__ Spart, const float* __restrict__ sumsq,
    float* __restrict__ attn)
{
    const int bh = blockIdx.x;
    const int b = bh >> 3, h = bh & 7;
    const int r = threadIdx.x;
    __shared__ float srk[64];
    const float rq = 1.0f / fmaxf(sqrtf(sumsq[b * DIMC + h * 64 + r]), EPSN);
    srk[r] = 1.0f / fmaxf(sqrtf(sumsq[4096 + b * DIMC + h * 64 + r]), EPSN);
    __syncthreads();
    const float* Sp = Spart + ((size_t)(bh * 8) << 12) + r * 64;

    float row[64];
    #pragma unroll 8
    for (int c = 0; c < 64; ++c) {
        float s = 0.f;
        #pragma unroll
        for (int ch = 0; ch < 8; ++ch) s += Sp[((size_t)ch << 12) + c];
        row[c] = s * SCALE * rq * srk[c];
    }
    float mx = -1e30f;
    #pragma unroll 8
    for (int c = 0; c < 64; ++c) mx = fmaxf(mx, row[c]);
    float sum = 0.f;
    #pragma unroll 8
    for (int c = 0; c < 64; ++c) { row[c] = __expf(row[c] - mx); sum += row[c]; }
    const float inv = 1.0f / sum;
    float* A = attn + ((size_t)bh << 12) + r * 64;
    #pragma unroll 8
    for (int c = 0; c < 64; ++c) A[c] = row[c] * inv;
}

// ---------------------------------------------------------------------------
// K5: fold Wp through attn -> Wp2b bf16 [b][j][c]
// ---------------------------------------------------------------------------
__global__ __launch_bounds__(256) void build_wp2(
    const float* __restrict__ Wp, const float* __restrict__ attn,
    unsigned short* __restrict__ Wp2b)
{
    const int jt = blockIdx.x;
    const int h  = blockIdx.y;
    const int b  = blockIdx.z;

    __shared__ float sA[64][64];
    __shared__ float sW[64][64];

    const int t = threadIdx.x;
    {
        const float* A = attn + ((size_t)(b * 8 + h) << 12);
        for (int i = t * 4; i < 4096; i += 1024)
            *(float4*)&sA[0][i] = *(const float4*)(A + i);
    }
    {
        const int j  = t >> 2;
        const int c0 = (t & 3) * 16;
        #pragma unroll
        for (int i = 0; i < 4; ++i) {
            float4 w4 = *(const float4*)(Wp + (size_t)(jt * 64 + j) * DIMC + h * 64 + c0 + i * 4);
            sW[c0 + i * 4 + 0][j] = w4.x; sW[c0 + i * 4 + 1][j] = w4.y;
            sW[c0 + i * 4 + 2][j] = w4.z; sW[c0 + i * 4 + 3][j] = w4.w;
        }
    }
    __syncthreads();

    const int tx = t & 15, ty = t >> 4;
    float acc[4][4] = {};
    #pragma unroll 16
    for (int c = 0; c < 64; ++c) {
        float wf[4], af[4];
        #pragma unroll
        for (int i = 0; i < 4; ++i) { wf[i] = sW[c][ty * 4 + i]; af[i] = sA[c][tx * 4 + i]; }
        #pragma unroll
        for (int r = 0; r < 4; ++r)
            #pragma unroll
            for (int cc = 0; cc < 4; ++cc)
                acc[r][cc] = fmaf(wf[r], af[cc], acc[r][cc]);
    }

    unsigned short* O = Wp2b + ((size_t)b * DIMC + jt * 64 + ty * 4) * DIMC + h * 64 + tx * 4;
    #pragma unroll
    for (int r = 0; r < 4; ++r) {
        ushort4 o4;
        o4.x = f2bf(acc[r][0]); o4.y = f2bf(acc[r][1]);
        o4.z = f2bf(acc[r][2]); o4.w = f2bf(acc[r][3]);
        *(ushort4*)(O + (size_t)r * DIMC) = o4;
    }
}

// ---------------------------------------------------------------------------
// K6: final MFMA GEMM: out[b][j][n] = sum_c Wp2b[b][j][c] * vT[b][n][c]
// fp32 stores are 64B line-granular (lane&15 consecutive) -- no staging needed
// ---------------------------------------------------------------------------
__global__ __launch_bounds__(256) void final_mfma(
    const unsigned short* __restrict__ Wp2b, const unsigned short* __restrict__ vT,
    float* __restrict__ out)
{
    const int b  = blockIdx.z;
    const int j0 = blockIdx.y * 64;
    const int n0 = blockIdx.x * 128;
    const unsigned short* A = Wp2b + (size_t)b * DIMC * DIMC;
    const unsigned short* B = vT + (size_t)b * HW * DIMC;

    __shared__ unsigned short sA[64 * 64];
    __shared__ unsigned short sB[128 * 64];

    const int t = threadIdx.x, lane = t & 63, w = t >> 6;
    const int wm = w >> 1, wn = w & 1;

    f32x4 zero = {0.f, 0.f, 0.f, 0.f};
    f32x4 acc[2][4];
    #pragma unroll
    for (int m = 0; m < 2; ++m)
        #pragma unroll
        for (int n = 0; n < 4; ++n) acc[m][n] = zero;

    int offA[2], offB[4];
    const unsigned short* gA[2];
    const unsigned short* gB[4];
    #pragma unroll
    for (int i = 0; i < 2; ++i) {
        int ch = t + i * 256, r = ch >> 3, sl = ch & 7;
        offA[i] = r * 128 + ((sl ^ (r & 7)) << 4);
        gA[i] = A + (size_t)(j0 + r) * DIMC + sl * 8;
    }
    #pragma unroll
    for (int i = 0; i < 4; ++i) {
        int ch = t + i * 256, r = ch >> 3, sl = ch & 7;
        offB[i] = r * 128 + ((sl ^ (r & 7)) << 4);
        gB[i] = B + (size_t)(n0 + r) * DIMC + sl * 8;
    }

    int4 ra[2], rb[4];
    #pragma unroll
    for (int i = 0; i < 2; ++i) ra[i] = *(const int4*)(gA[i]);
    #pragma unroll
    for (int i = 0; i < 4; ++i) rb[i] = *(const int4*)(gB[i]);

    for (int c0 = 0; c0 < DIMC; c0 += 64) {
        __syncthreads();
        #pragma unroll
        for (int i = 0; i < 2; ++i) *(int4*)((char*)sA + offA[i]) = ra[i];
        #pragma unroll
        for (int i = 0; i < 4; ++i) *(int4*)((char*)sB + offB[i]) = rb[i];
        __syncthreads();
        if (c0 + 64 < DIMC) {
            #pragma unroll
            for (int i = 0; i < 2; ++i) ra[i] = *(const int4*)(gA[i] + c0 + 64);
            #pragma unroll
            for (int i = 0; i < 4; ++i) rb[i] = *(const int4*)(gB[i] + c0 + 64);
        }
        #pragma unroll
        for (int s = 0; s < 2; ++s) {
            bf16x8 af[2], bfr[4];
            #pragma unroll
            for (int m = 0; m < 2; ++m) {
                int r = wm * 32 + m * 16 + (lane & 15);
                int byte = r * 128 + s * 64 + ((lane >> 4) << 4);
                byte ^= (r & 7) << 4;
                af[m] = *(const bf16x8*)((const char*)sA + byte);
            }
            #pragma unroll
            for (int n = 0; n < 4; ++n) {
                int r = wn * 64 + n * 16 + (lane & 15);
                int byte = r * 128 + s * 64 + ((lane >> 4) << 4);
                byte ^= (r & 7) << 4;
                bfr[n] = *(const bf16x8*)((const char*)sB + byte);
            }
            #pragma unroll
            for (int m = 0; m < 2; ++m)
                #pragma unroll
                for (int n = 0; n < 4; ++n)
                    acc[m][n] = __builtin_amdgcn_mfma_f32_16x16x32_bf16(
                        af[m], bfr[n], acc[m][n], 0, 0, 0);
        }
    }

    #pragma unroll
    for (int m = 0; m < 2; ++m)
        #pragma unroll
        for (int r4 = 0; r4 < 4; ++r4) {
            int j = j0 + wm * 32 + m * 16 + ((lane >> 4) << 2) + r4;
            size_t rowbase = ((size_t)b * DIMC + j) * HW + n0 + wn * 64 + (lane & 15);
            #pragma unroll
            for (int n = 0; n < 4; ++n)
                out[rowbase + n * 16] = acc[m][n][r4];
        }
}

// ---------------------------------------------------------------------------
// Workspace (bytes):
//   xT    @ 0           33,554,432
//   q     @ 33554432    33,554,432
//   k     @ 67108864    33,554,432
//   vT    @ 100663296   33,554,432
//   Wb    @ 134217728    1,572,864
//   Wp2b  @ 135790592    4,194,304
//   sumsq @ 139984896       32,768   (q rows then k rows, zeroed each call)
//   Spart @ 140017664    8,388,608
//   attn  @ 148406272    1,048,576
//   end ~149.5 MB
// ---------------------------------------------------------------------------
extern "C" void kernel_launch(void* const* d_in, const int* in_sizes, int n_in,
                              void* d_out, int out_size, void* d_ws, size_t ws_size,
                              hipStream_t stream)
{
    const float* x    = (const float*)d_in[0];
    const float* mask = (const float*)d_in[1];
    const float* Wq   = (const float*)d_in[2];
    const float* Wk   = (const float*)d_in[3];
    const float* Wv   = (const float*)d_in[4];
    const float* Wp   = (const float*)d_in[5];
    float* out = (float*)d_out;
    char* wsb = (char*)d_ws;

    unsigned short* xT   = (unsigned short*)(wsb + 0);
    unsigned short* q    = (unsigned short*)(wsb + 33554432);
    unsigned short* k    = (unsigned short*)(wsb + 67108864);
    unsigned short* vT   = (unsigned short*)(wsb + 100663296);
    unsigned short* Wb   = (unsigned short*)(wsb + 134217728);
    unsigned short* Wp2b = (unsigned short*)(wsb + 135790592);
    float* sumsq = (float*)(wsb + 139984896);
    float* Spart = (float*)(wsb + 140017664);
    float* attn  = (float*)(wsb + 148406272);

    hipMemsetAsync(sumsq, 0, 2 * 4096 * sizeof(float), stream);

    convert_w    <<<768,              256, 0, stream>>>(Wq, Wk, Wv, Wb);
    transpose_x  <<<dim3(64, 8, 8),   256, 0, stream>>>(x, xT);
    qkv_mfma     <<<dim3(32, 8, 8),   256, 0, stream>>>(Wb, xT, mask, q, k, vT, sumsq);
    attn_mfma    <<<dim3(64, 8),      256, 0, stream>>>(q, k, Spart);
    softmax_attn <<<64,                64, 0, stream>>>(Spart, sumsq, attn);
    build_wp2    <<<dim3(8, 8, 8),    256, 0, stream>>>(Wp, attn, Wp2b);
    final_mfma   <<<dim3(32, 8, 8),   256, 0, stream>>>(Wp2b, vT, out);
}